// Round 21
// baseline (317.078 us; speedup 1.0000x reference)
//
#include <hip/hip_runtime.h>
#include <hip/hip_bf16.h>

// GIN classifier. R20: R19 (best, 315.6us) + dispatch repacking: hist moved
// to D1 (idle capacity; ideg pre-zeroed by memsetAsync), scan1 fused into the
// gemm1 dispatch (rides free). Gather (16-wide + own-row prefetch) and gemm1
// kernel bodies byte-identical to R19.

#define N_NODES 100000
#define N_EDGES 800000
#define N_GRAPHS 128
#define NB_SCAN 391   // ceil(N_NODES/256)
#define LDP 136       // bf16 LDS row stride: 2-way bank alias only (free)
#define FLDP 68       // f32 row stride for pool staging
#define G1_BLOCKS 1563
#define HIST_BLOCKS 782   // 782*1024 >= 800000
#define WT_BLOCKS 903     // wt 480 + ideg... (kept: wt 122880 + pooled -> 903*256)

typedef __bf16 bf16x8 __attribute__((ext_vector_type(8)));
typedef float f32x4 __attribute__((ext_vector_type(4)));
typedef unsigned short ushort_t;
typedef unsigned int uint_t;

static __device__ __forceinline__ ushort_t f2b(float f) {
    uint_t u = __builtin_bit_cast(uint_t, f);
    uint_t r = (u + 0x7fffu + ((u >> 16) & 1u)) >> 16;   // RNE
    return (ushort_t)r;
}
static __device__ __forceinline__ float b2f(ushort_t u) {
    return __builtin_bit_cast(float, (uint_t)u << 16);
}

static __device__ __forceinline__ void gload16(const void* gp, void* lp) {
    __builtin_amdgcn_global_load_lds(
        (const __attribute__((address_space(1))) void*)gp,
        (__attribute__((address_space(3))) void*)lp, 16, 0, 0);
}

// ---- D1: weight transposes + zero pooled + CSR histogram (ideg pre-zeroed) -
__global__ __launch_bounds__(256) void wt_hist_k(
        const float* __restrict__ w1a, const float* __restrict__ w1b,
        const float* __restrict__ w2a, const float* __restrict__ w2b,
        const float* __restrict__ w3a, const float* __restrict__ w3b,
        ushort_t* __restrict__ o1a, ushort_t* __restrict__ o1b,
        ushort_t* __restrict__ o2a, ushort_t* __restrict__ o2b,
        ushort_t* __restrict__ o3a, ushort_t* __restrict__ o3b,
        float* __restrict__ pooled,
        const int* __restrict__ dst, int* __restrict__ ideg) {
    if (blockIdx.x >= WT_BLOCKS) {
        int b = blockIdx.x - WT_BLOCKS;
        int e0 = b * 1024 + threadIdx.x;
        #pragma unroll
        for (int p = 0; p < 4; ++p) {
            int e = e0 + p * 256;
            if (e < N_EDGES) atomicAdd(&ideg[dst[e]], 1);
        }
        return;
    }
    int t = blockIdx.x * 256 + threadIdx.x;
    if (t < 122880) {
        const float* W; ushort_t* O; int K, N, i;
        if      (t <  49152) { W = w1a; O = o1a; K = 384; N = 128; i = t; }
        else if (t <  65536) { W = w1b; O = o1b; K = 128; N = 128; i = t - 49152; }
        else if (t <  81920) { W = w2a; O = o2a; K = 128; N = 128; i = t - 65536; }
        else if (t <  98304) { W = w2b; O = o2b; K = 128; N = 128; i = t - 81920; }
        else if (t < 114688) { W = w3a; O = o3a; K = 128; N = 128; i = t - 98304; }
        else                 { W = w3b; O = o3b; K = 128; N = 64;  i = t - 114688; }
        int k = i / N, c = i % N;
        O[c * K + k] = f2b(W[i]);
    } else if (t < 131072) {
        pooled[t - 122880] = 0.f;
    }
}

// ---- D2: gemm1 (counted-vmcnt stream, R19) + scan1 (ideg complete) ---------
__global__ __launch_bounds__(256) void gemm1_scan1_k(const float* __restrict__ A,
                                                     const ushort_t* __restrict__ Wt,
                                                     ushort_t* __restrict__ C, int M,
                                                     const int* __restrict__ deg,
                                                     int* __restrict__ tmp,
                                                     int* __restrict__ bsum) {
    __shared__ __align__(16) float    Af[4][2048];   // 4 x 8 KB (64 rows x 32 k)
    __shared__ __align__(16) ushort_t Bl[4][4096];   // 4 x 8 KB (128 cols x 32 k)

    if (blockIdx.x >= G1_BLOCKS) {
        // ---- scan1 role ----
        int b = blockIdx.x - G1_BLOCKS;              // 0..390
        int* s = (int*)&Af[0][0];
        int i = b * 256 + threadIdx.x;
        int t = threadIdx.x;
        s[t] = (i < N_NODES) ? deg[i] : 0;
        __syncthreads();
        for (int off = 1; off < 256; off <<= 1) {
            int v = (t >= off) ? s[t - off] : 0;
            __syncthreads();
            s[t] += v;
            __syncthreads();
        }
        if (i < N_NODES) tmp[i] = s[t];
        if (t == 255) bsum[b] = s[255];
        return;
    }

    constexpr int K = 384;
    const int tid  = threadIdx.x;
    const int lane = tid & 63;
    const int wid  = tid >> 6;
    const int wrow = wid >> 1;
    const int wcol = wid & 1;
    const int l15  = lane & 15;
    const int kg   = lane >> 4;
    const int row0 = blockIdx.x * 64;

    const int R0 = tid >> 3, cu = tid & 7;
    const int R1 = R0 + 32;
    int gr0 = row0 + R0; if (gr0 > M - 1) gr0 = M - 1;
    int gr1 = row0 + R1; if (gr1 > M - 1) gr1 = M - 1;
    const int as0 = (cu ^ (R0 & 7)) * 4;
    const int as1 = (cu ^ (R1 & 7)) * 4;
    const int col0 = tid >> 2, bu = tid & 3;
    const int col1 = col0 + 64;
    const int bs0 = (bu ^ (col0 & 3)) * 8;
    const int bs1 = (bu ^ (col1 & 3)) * 8;

    f32x4 acc[2][4];
    #pragma unroll
    for (int i = 0; i < 2; ++i)
        #pragma unroll
        for (int j = 0; j < 4; ++j)
            acc[i][j] = f32x4{0.f, 0.f, 0.f, 0.f};

    #pragma unroll
    for (int p = 0; p < 2; ++p) {
        int k0 = p * 32;
        gload16(A + (size_t)gr0 * K + k0 + as0, &Af[p][wid * 256]);
        gload16(A + (size_t)gr1 * K + k0 + as1, &Af[p][1024 + wid * 256]);
        gload16(Wt + (size_t)col0 * K + k0 + bs0, &Bl[p][wid * 512]);
        gload16(Wt + (size_t)col1 * K + k0 + bs1, &Bl[p][2048 + wid * 512]);
    }

    const int rA0 = wrow * 32 + l15;
    const int rA1 = rA0 + 16;
    const int sw0 = rA0 & 7;

    #pragma unroll
    for (int t = 0; t < 12; ++t) {
        if (t + 2 < 12) {
            int k0 = (t + 2) * 32;
            int buf = (t + 2) & 3;
            gload16(A + (size_t)gr0 * K + k0 + as0, &Af[buf][wid * 256]);
            gload16(A + (size_t)gr1 * K + k0 + as1, &Af[buf][1024 + wid * 256]);
            gload16(Wt + (size_t)col0 * K + k0 + bs0, &Bl[buf][wid * 512]);
            gload16(Wt + (size_t)col1 * K + k0 + bs1, &Bl[buf][2048 + wid * 512]);
        }
        if (t < 10)       asm volatile("s_waitcnt vmcnt(8)" ::: "memory");
        else if (t == 10) asm volatile("s_waitcnt vmcnt(4)" ::: "memory");
        else              asm volatile("s_waitcnt vmcnt(0)" ::: "memory");
        __builtin_amdgcn_s_barrier();
        __builtin_amdgcn_sched_barrier(0);

        const float*    Ab = Af[t & 3];
        const ushort_t* Bb = Bl[t & 3];
        float4 lo0 = *reinterpret_cast<const float4*>(Ab + rA0 * 32 + (((kg * 2)     ^ sw0) * 4));
        float4 hi0 = *reinterpret_cast<const float4*>(Ab + rA0 * 32 + (((kg * 2 + 1) ^ sw0) * 4));
        float4 lo1 = *reinterpret_cast<const float4*>(Ab + rA1 * 32 + (((kg * 2)     ^ sw0) * 4));
        float4 hi1 = *reinterpret_cast<const float4*>(Ab + rA1 * 32 + (((kg * 2 + 1) ^ sw0) * 4));
        bf16x8 a0, a1;
        a0[0] = (__bf16)lo0.x; a0[1] = (__bf16)lo0.y; a0[2] = (__bf16)lo0.z; a0[3] = (__bf16)lo0.w;
        a0[4] = (__bf16)hi0.x; a0[5] = (__bf16)hi0.y; a0[6] = (__bf16)hi0.z; a0[7] = (__bf16)hi0.w;
        a1[0] = (__bf16)lo1.x; a1[1] = (__bf16)lo1.y; a1[2] = (__bf16)lo1.z; a1[3] = (__bf16)lo1.w;
        a1[4] = (__bf16)hi1.x; a1[5] = (__bf16)hi1.y; a1[6] = (__bf16)hi1.z; a1[7] = (__bf16)hi1.w;
        #pragma unroll
        for (int j = 0; j < 4; ++j) {
            int col = wcol * 64 + j * 16 + l15;
            bf16x8 b = *reinterpret_cast<const bf16x8*>(Bb + col * 32 + ((kg ^ (col & 3)) * 8));
            acc[0][j] = __builtin_amdgcn_mfma_f32_16x16x32_bf16(a0, b, acc[0][j], 0, 0, 0);
            acc[1][j] = __builtin_amdgcn_mfma_f32_16x16x32_bf16(a1, b, acc[1][j], 0, 0, 0);
        }
    }

    __syncthreads();
    ushort_t* Es = (ushort_t*)&Af[0][0];
    #pragma unroll
    for (int i = 0; i < 2; ++i)
        #pragma unroll
        for (int j = 0; j < 4; ++j) {
            int col = wcol * 64 + j * 16 + l15;
            #pragma unroll
            for (int q = 0; q < 4; ++q) {
                int row = wrow * 32 + i * 16 + kg * 4 + q;
                Es[row * LDP + col] = f2b(acc[i][j][q]);
            }
        }
    __syncthreads();
    #pragma unroll
    for (int p = 0; p < 4; ++p) {
        int idx = tid + p * 256;
        int rr = idx >> 4, c16 = idx & 15;
        int gr = row0 + rr;
        if (gr < M)
            *reinterpret_cast<uint4*>(C + (size_t)gr * 128 + c16 * 8) =
                *reinterpret_cast<const uint4*>(&Es[rr * LDP + c16 * 8]);
    }
}

// ---------------- CSR scan tail ----------------
__global__ __launch_bounds__(256) void scan23_k(const int* __restrict__ tmp,
                                                const int* __restrict__ deg,
                                                const int* __restrict__ bsum,
                                                int* __restrict__ row_start) {
    __shared__ int sb[256];
    int t = threadIdx.x;
    int partial = 0;
    for (int i = t; i < (int)blockIdx.x; i += 256) partial += bsum[i];
    sb[t] = partial;
    __syncthreads();
    for (int off = 128; off > 0; off >>= 1) {
        if (t < off) sb[t] += sb[t + off];
        __syncthreads();
    }
    int boff = sb[0];
    int i = blockIdx.x * 256 + t;
    if (i < N_NODES) row_start[i] = tmp[i] - deg[i] + boff;
}

__global__ __launch_bounds__(256) void fill_k(const int* __restrict__ src,
                                              const int* __restrict__ dst,
                                              int* __restrict__ row_start,
                                              int* __restrict__ csr_src) {
    int e = blockIdx.x * 256 + threadIdx.x;
    if (e >= N_EDGES) return;
    int idx = atomicAdd(&row_start[dst[e]], 1);
    csr_src[idx] = src[e];
}

// ======== fused layer: gather(16-wide batches, own-row prefetch)+BN+ReLU ->
//          LDS -> GEMM1(+b,relu) -> [TAIL: pool] or [GEMM2 -> Yout] =========
template<bool TAIL>
__global__ __launch_bounds__(256) void gather_mlp_k(
        const ushort_t* __restrict__ Yin,
        const int* __restrict__ csr, const int* __restrict__ rend,
        const int* __restrict__ deg,
        const float* __restrict__ epsp, const float* __restrict__ ba,
        const float* __restrict__ g, const float* __restrict__ be,
        const float* __restrict__ mm, const float* __restrict__ vv,
        const ushort_t* __restrict__ Wb, const float* __restrict__ bias1,
        const ushort_t* __restrict__ Wa2,
        ushort_t* __restrict__ Yout,
        const int* __restrict__ batch, float* __restrict__ pooled, int M) {
    constexpr int NJ1 = TAIL ? 2 : 4;       // N1 = 64 or 128
    __shared__ ushort_t Hl[64 * LDP];
    __shared__ ushort_t Xl[64 * LDP];       // f32 pool staging view for TAIL
    float* Fl = (float*)Xl;

    const int tid  = threadIdx.x;
    const int lane = tid & 63;
    const int wid  = tid >> 6;
    const int l15  = lane & 15;
    const int slot = lane >> 4;
    const int c0   = l15 * 8;
    const int row0 = blockIdx.x * 64;

    // ---- phase G: gather + BN + ReLU -> Hl (wave w owns rows w*16..w*16+15)
    {
        float ep = 1.0f + epsp[0];
        float sc[8], sh[8];
        #pragma unroll
        for (int jj = 0; jj < 8; ++jj) {
            int c = c0 + jj;
            float s = g[c] * rsqrtf(vv[c] + 1e-5f);
            sc[jj] = s;
            sh[jj] = (ba[c] - mm[c]) * s + be[c];
        }

        const int base = row0 + wid * 16;
        int cn = base; if (cn > M - 1) cn = M - 1;
        int end = rend[cn], d = deg[cn];
        int st = end - d;
        int nlim = (d > 64) ? 64 : d;
        int nb = (lane < nlim) ? csr[st + lane] : 0;
        uint4 ow = *reinterpret_cast<const uint4*>(Yin + (size_t)cn * 128 + c0);

        for (int nl = 0; nl < 16; ++nl) {
            int nxt = base + nl + 1; if (nxt > M - 1) nxt = M - 1;
            int nend = 0, nd = 0;
            if (nl < 15) { nend = rend[nxt]; nd = deg[nxt]; }   // prefetch meta

            float acc[8] = {0.f, 0.f, 0.f, 0.f, 0.f, 0.f, 0.f, 0.f};
            // 16 neighbors per iteration: 4 independent row loads per lane
            for (int j0 = 0; j0 < nlim; j0 += 16) {
                int jA = j0 + slot;
                int jB = j0 + 4 + slot;
                int jC = j0 + 8 + slot;
                int jD = j0 + 12 + slot;
                int iA = __shfl(nb, jA & 63);
                int iB = __shfl(nb, jB & 63);
                int iC = __shfl(nb, jC & 63);
                int iD = __shfl(nb, jD & 63);
                uint4 wa = *reinterpret_cast<const uint4*>(Yin + (size_t)iA * 128 + c0);
                uint4 wb = *reinterpret_cast<const uint4*>(Yin + (size_t)iB * 128 + c0);
                uint4 wc4 = *reinterpret_cast<const uint4*>(Yin + (size_t)iC * 128 + c0);
                uint4 wd = *reinterpret_cast<const uint4*>(Yin + (size_t)iD * 128 + c0);
                float fa = (jA < nlim) ? 1.f : 0.f;
                float fb = (jB < nlim) ? 1.f : 0.f;
                float fc = (jC < nlim) ? 1.f : 0.f;
                float fd = (jD < nlim) ? 1.f : 0.f;
                uint_t ua[4] = {wa.x, wa.y, wa.z, wa.w};
                uint_t ub[4] = {wb.x, wb.y, wb.z, wb.w};
                uint_t uc[4] = {wc4.x, wc4.y, wc4.z, wc4.w};
                uint_t ud[4] = {wd.x, wd.y, wd.z, wd.w};
                #pragma unroll
                for (int p = 0; p < 4; ++p) {
                    acc[2 * p]     += fa * b2f((ushort_t)(ua[p] & 0xffff));
                    acc[2 * p + 1] += fa * b2f((ushort_t)(ua[p] >> 16));
                    acc[2 * p]     += fb * b2f((ushort_t)(ub[p] & 0xffff));
                    acc[2 * p + 1] += fb * b2f((ushort_t)(ub[p] >> 16));
                    acc[2 * p]     += fc * b2f((ushort_t)(uc[p] & 0xffff));
                    acc[2 * p + 1] += fc * b2f((ushort_t)(uc[p] >> 16));
                    acc[2 * p]     += fd * b2f((ushort_t)(ud[p] & 0xffff));
                    acc[2 * p + 1] += fd * b2f((ushort_t)(ud[p] >> 16));
                }
            }
            for (int j = st + 64; j < end; ++j) {
                if (slot == 0) {
                    int idx = csr[j];
                    uint4 w = *reinterpret_cast<const uint4*>(Yin + (size_t)idx * 128 + c0);
                    uint_t uw[4] = {w.x, w.y, w.z, w.w};
                    #pragma unroll
                    for (int p = 0; p < 4; ++p) {
                        acc[2 * p]     += b2f((ushort_t)(uw[p] & 0xffff));
                        acc[2 * p + 1] += b2f((ushort_t)(uw[p] >> 16));
                    }
                }
            }

            // prefetch next node's indices + own row (overlaps reduce+BN+store)
            int nst = nend - nd;
            int nnlim = (nd > 64) ? 64 : nd;
            int nb2 = 0;
            uint4 ow2 = make_uint4(0, 0, 0, 0);
            if (nl < 15) {
                if (lane < nnlim) nb2 = csr[nst + lane];
                ow2 = *reinterpret_cast<const uint4*>(Yin + (size_t)nxt * 128 + c0);
            }

            #pragma unroll
            for (int jj = 0; jj < 8; ++jj) {
                acc[jj] += __shfl_xor(acc[jj], 16);
                acc[jj] += __shfl_xor(acc[jj], 32);
            }
            uint_t uo[4] = {ow.x, ow.y, ow.z, ow.w};
            ushort_t rr[8];
            #pragma unroll
            for (int p = 0; p < 4; ++p) {
                float o0 = b2f((ushort_t)(uo[p] & 0xffff));
                float o1 = b2f((ushort_t)(uo[p] >> 16));
                float t0 = sc[2 * p] * (ep * o0 + acc[2 * p]) + sh[2 * p];
                float t1 = sc[2 * p + 1] * (ep * o1 + acc[2 * p + 1]) + sh[2 * p + 1];
                rr[2 * p]     = f2b(fmaxf(t0, 0.f));
                rr[2 * p + 1] = f2b(fmaxf(t1, 0.f));
            }
            if (slot == 0) {
                uint4 packed;
                packed.x = (uint_t)rr[0] | ((uint_t)rr[1] << 16);
                packed.y = (uint_t)rr[2] | ((uint_t)rr[3] << 16);
                packed.z = (uint_t)rr[4] | ((uint_t)rr[5] << 16);
                packed.w = (uint_t)rr[6] | ((uint_t)rr[7] << 16);
                *reinterpret_cast<uint4*>(&Hl[(wid * 16 + nl) * LDP + c0]) = packed;
            }

            end = nend; d = nd; st = nst; nlim = nnlim; nb = nb2; ow = ow2;
        }
    }
    __syncthreads();

    // ---- MLP phase ----
    const int wrow = wid >> 1;
    const int wcol = wid & 1;
    const int kg   = lane >> 4;

    f32x4 acc1[2][NJ1];
    #pragma unroll
    for (int i = 0; i < 2; ++i)
        #pragma unroll
        for (int j = 0; j < NJ1; ++j)
            acc1[i][j] = f32x4{0.f, 0.f, 0.f, 0.f};
    #pragma unroll
    for (int kk = 0; kk < 4; ++kk) {
        bf16x8 a0 = *reinterpret_cast<const bf16x8*>(&Hl[(wrow * 32 + l15) * LDP + kk * 32 + kg * 8]);
        bf16x8 a1 = *reinterpret_cast<const bf16x8*>(&Hl[(wrow * 32 + 16 + l15) * LDP + kk * 32 + kg * 8]);
        #pragma unroll
        for (int j = 0; j < NJ1; ++j) {
            int col = wcol * (16 * NJ1) + j * 16 + l15;
            bf16x8 b = *reinterpret_cast<const bf16x8*>(Wb + (size_t)col * 128 + kk * 32 + kg * 8);
            acc1[0][j] = __builtin_amdgcn_mfma_f32_16x16x32_bf16(a0, b, acc1[0][j], 0, 0, 0);
            acc1[1][j] = __builtin_amdgcn_mfma_f32_16x16x32_bf16(a1, b, acc1[1][j], 0, 0, 0);
        }
    }

    if constexpr (TAIL) {
        #pragma unroll
        for (int i = 0; i < 2; ++i)
            #pragma unroll
            for (int j = 0; j < NJ1; ++j) {
                int col = wcol * 32 + j * 16 + l15;
                float bi = bias1[col];
                #pragma unroll
                for (int q = 0; q < 4; ++q) {
                    int row = wrow * 32 + i * 16 + kg * 4 + q;
                    Fl[row * FLDP + col] = fmaxf(acc1[i][j][q] + bi, 0.f);
                }
            }
        __syncthreads();
        int col = tid & 63;
        int qq  = tid >> 6;
        float a = 0.f;
        int cur = -1;
        for (int rr2 = 0; rr2 < 16; ++rr2) {
            int r = qq * 16 + rr2;
            int gr = row0 + r;
            if (gr >= M) break;
            int b = batch[gr];
            if (b != cur) {
                if (cur >= 0) atomicAdd(&pooled[cur * 64 + col], a);
                a = 0.f;
                cur = b;
            }
            a += Fl[r * FLDP + col];
        }
        if (cur >= 0) atomicAdd(&pooled[cur * 64 + col], a);
    } else {
        #pragma unroll
        for (int i = 0; i < 2; ++i)
            #pragma unroll
            for (int j = 0; j < NJ1; ++j) {
                int col = wcol * 64 + j * 16 + l15;
                float bi = bias1[col];
                #pragma unroll
                for (int q = 0; q < 4; ++q) {
                    int row = wrow * 32 + i * 16 + kg * 4 + q;
                    Xl[row * LDP + col] = f2b(fmaxf(acc1[i][j][q] + bi, 0.f));
                }
            }
        __syncthreads();

        f32x4 acc2[2][4];
        #pragma unroll
        for (int i = 0; i < 2; ++i)
            #pragma unroll
            for (int j = 0; j < 4; ++j)
                acc2[i][j] = f32x4{0.f, 0.f, 0.f, 0.f};
        #pragma unroll
        for (int kk = 0; kk < 4; ++kk) {
            bf16x8 a0 = *reinterpret_cast<const bf16x8*>(&Xl[(wrow * 32 + l15) * LDP + kk * 32 + kg * 8]);
            bf16x8 a1 = *reinterpret_cast<const bf16x8*>(&Xl[(wrow * 32 + 16 + l15) * LDP + kk * 32 + kg * 8]);
            #pragma unroll
            for (int j = 0; j < 4; ++j) {
                int col = wcol * 64 + j * 16 + l15;
                bf16x8 b = *reinterpret_cast<const bf16x8*>(Wa2 + (size_t)col * 128 + kk * 32 + kg * 8);
                acc2[0][j] = __builtin_amdgcn_mfma_f32_16x16x32_bf16(a0, b, acc2[0][j], 0, 0, 0);
                acc2[1][j] = __builtin_amdgcn_mfma_f32_16x16x32_bf16(a1, b, acc2[1][j], 0, 0, 0);
            }
        }
        __syncthreads();   // Hl reads (GEMM1) done; reuse Hl for output staging
        #pragma unroll
        for (int i = 0; i < 2; ++i)
            #pragma unroll
            for (int j = 0; j < 4; ++j) {
                int col = wcol * 64 + j * 16 + l15;
                #pragma unroll
                for (int q = 0; q < 4; ++q) {
                    int row = wrow * 32 + i * 16 + kg * 4 + q;
                    Hl[row * LDP + col] = f2b(acc2[i][j][q]);
                }
            }
        __syncthreads();
        #pragma unroll
        for (int p = 0; p < 4; ++p) {
            int idx = tid + p * 256;
            int r = idx >> 4, c16 = idx & 15;
            int gr = row0 + r;
            if (gr < M)
                *reinterpret_cast<uint4*>(Yout + (size_t)gr * 128 + c16 * 8) =
                    *reinterpret_cast<const uint4*>(&Hl[r * LDP + c16 * 8]);
        }
    }
}

// ---------------- classifier ----------------
__global__ __launch_bounds__(256) void classifier_k(const float* __restrict__ pooled,
                                                    const float* __restrict__ wc,
                                                    const float* __restrict__ bc,
                                                    float* __restrict__ out) {
    int t = threadIdx.x;
    int gidx = t >> 1, c = t & 1;
    float s = bc[c];
    #pragma unroll
    for (int k = 0; k < 64; ++k)
        s += pooled[gidx * 64 + k] * wc[k * 2 + c];
    out[gidx * 2 + c] = s;
}

extern "C" void kernel_launch(void* const* d_in, const int* in_sizes, int n_in,
                              void* d_out, int out_size, void* d_ws, size_t ws_size,
                              hipStream_t stream) {
    const float* x     = (const float*)d_in[0];
    const int*   ei    = (const int*)d_in[1];
    const int*   src   = ei;
    const int*   dst   = ei + N_EDGES;
    const int*   batch = (const int*)d_in[2];
    const float* eps1 = (const float*)d_in[3];
    const float* w1a  = (const float*)d_in[4];
    const float* b1a  = (const float*)d_in[5];
    const float* g1   = (const float*)d_in[6];
    const float* be1  = (const float*)d_in[7];
    const float* m1   = (const float*)d_in[8];
    const float* v1   = (const float*)d_in[9];
    const float* w1b  = (const float*)d_in[10];
    const float* b1b  = (const float*)d_in[11];
    const float* eps2 = (const float*)d_in[12];
    const float* w2a  = (const float*)d_in[13];
    const float* b2a  = (const float*)d_in[14];
    const float* g2   = (const float*)d_in[15];
    const float* be2  = (const float*)d_in[16];
    const float* m2   = (const float*)d_in[17];
    const float* v2   = (const float*)d_in[18];
    const float* w2b  = (const float*)d_in[19];
    const float* b2b  = (const float*)d_in[20];
    const float* eps3 = (const float*)d_in[21];
    const float* w3a  = (const float*)d_in[22];
    const float* b3a  = (const float*)d_in[23];
    const float* g3   = (const float*)d_in[24];
    const float* be3  = (const float*)d_in[25];
    const float* m3   = (const float*)d_in[26];
    const float* v3   = (const float*)d_in[27];
    const float* w3b  = (const float*)d_in[28];
    const float* b3b  = (const float*)d_in[29];
    const float* wc   = (const float*)d_in[30];
    const float* bc   = (const float*)d_in[31];
    float* out = (float*)d_out;

    // workspace layout
    ushort_t* Y = (ushort_t*)d_ws;             // [100000,128] bf16
    ushort_t* H = Y + 12800000;                // [100000,128] bf16 (ping-pong)
    ushort_t* wt1a = H + 12800000;             // 384*128
    ushort_t* wt1b = wt1a + 49152;             // 128*128
    ushort_t* wt2a = wt1b + 16384;
    ushort_t* wt2b = wt2a + 16384;
    ushort_t* wt3a = wt2b + 16384;
    ushort_t* wt3b = wt3a + 16384;             // 64*128
    float* pooled = (float*)(wt3b + 8192);     // [128,64]
    int* ideg = (int*)(pooled + 8192);         // [100000]
    int* irow = ideg + N_NODES;
    int* itmp = irow + N_NODES;
    int* icsr = itmp + N_NODES;                // [800000]
    int* ibsum = icsr + N_EDGES;               // [391]

    const int M = N_NODES;
    const int gLayer = (M + 63) / 64;          // 1563
    const int gEdge = (N_EDGES + 255) / 256;   // 3125
    const int gNode = NB_SCAN;                 // 391

    // ---- D0/D1: zero ideg, then wt + pooled-zero + histogram ----
    hipMemsetAsync(ideg, 0, N_NODES * sizeof(int), stream);
    wt_hist_k<<<WT_BLOCKS + HIST_BLOCKS, 256, 0, stream>>>(
        w1a, w1b, w2a, w2b, w3a, w3b,
        wt1a, wt1b, wt2a, wt2b, wt3a, wt3b,
        pooled, dst, ideg);

    // ---- D2: gemm1 (counted-vmcnt stream) + scan1 ----
    gemm1_scan1_k<<<G1_BLOCKS + NB_SCAN, 256, 0, stream>>>(
        x, wt1a, Y, M, ideg, itmp, ibsum);

    // ---- D3-D4: scan tail + fill ----
    scan23_k<<<gNode, 256, 0, stream>>>(itmp, ideg, ibsum, irow);
    fill_k<<<gEdge, 256, 0, stream>>>(src, dst, irow, icsr);

    // ---- D5-D7: fused layers ----
    gather_mlp_k<false><<<gLayer, 256, 0, stream>>>(
        Y, icsr, irow, ideg, eps1, b1a, g1, be1, m1, v1,
        wt1b, b1b, wt2a, H, nullptr, nullptr, M);
    gather_mlp_k<false><<<gLayer, 256, 0, stream>>>(
        H, icsr, irow, ideg, eps2, b2a, g2, be2, m2, v2,
        wt2b, b2b, wt3a, Y, nullptr, nullptr, M);
    gather_mlp_k<true><<<gLayer, 256, 0, stream>>>(
        Y, icsr, irow, ideg, eps3, b3a, g3, be3, m3, v3,
        wt3b, b3b, nullptr, nullptr, batch, pooled, M);

    // ---- D8: classifier ----
    classifier_k<<<1, 256, 0, stream>>>(pooled, wc, bc, out);
}

// Round 22
// 314.982 us; speedup vs baseline: 1.0067x; 1.0067x over previous
//
#include <hip/hip_runtime.h>
#include <hip/hip_bf16.h>

// GIN classifier. R21: FINAL = exact R19 configuration (best measured,
// 315.6us). gemm1 counted-vmcnt stream + hist in D2; gather with 16-wide
// neighbor batches + own-row prefetch; per-layer fused gather+MLP; sorted
// -batch pool; CSR built on-device once.

#define N_NODES 100000
#define N_EDGES 800000
#define N_GRAPHS 128
#define NB_SCAN 391   // ceil(N_NODES/256)
#define LDP 136       // bf16 LDS row stride: 2-way bank alias only (free)
#define FLDP 68       // f32 row stride for pool staging
#define G1_BLOCKS 1563
#define HIST_BLOCKS 782   // 782*1024 >= 800000

typedef __bf16 bf16x8 __attribute__((ext_vector_type(8)));
typedef float f32x4 __attribute__((ext_vector_type(4)));
typedef unsigned short ushort_t;
typedef unsigned int uint_t;

static __device__ __forceinline__ ushort_t f2b(float f) {
    uint_t u = __builtin_bit_cast(uint_t, f);
    uint_t r = (u + 0x7fffu + ((u >> 16) & 1u)) >> 16;   // RNE
    return (ushort_t)r;
}
static __device__ __forceinline__ float b2f(ushort_t u) {
    return __builtin_bit_cast(float, (uint_t)u << 16);
}

static __device__ __forceinline__ void gload16(const void* gp, void* lp) {
    __builtin_amdgcn_global_load_lds(
        (const __attribute__((address_space(1))) void*)gp,
        (__attribute__((address_space(3))) void*)lp, 16, 0, 0);
}

// ---- weight transposes + zero ideg + zero pooled, one dispatch -------------
__global__ __launch_bounds__(256) void wt_all_k(
        const float* __restrict__ w1a, const float* __restrict__ w1b,
        const float* __restrict__ w2a, const float* __restrict__ w2b,
        const float* __restrict__ w3a, const float* __restrict__ w3b,
        ushort_t* __restrict__ o1a, ushort_t* __restrict__ o1b,
        ushort_t* __restrict__ o2a, ushort_t* __restrict__ o2b,
        ushort_t* __restrict__ o3a, ushort_t* __restrict__ o3b,
        int* __restrict__ ideg, float* __restrict__ pooled) {
    int t = blockIdx.x * 256 + threadIdx.x;
    if (t < 122880) {
        const float* W; ushort_t* O; int K, N, i;
        if      (t <  49152) { W = w1a; O = o1a; K = 384; N = 128; i = t; }
        else if (t <  65536) { W = w1b; O = o1b; K = 128; N = 128; i = t - 49152; }
        else if (t <  81920) { W = w2a; O = o2a; K = 128; N = 128; i = t - 65536; }
        else if (t <  98304) { W = w2b; O = o2b; K = 128; N = 128; i = t - 81920; }
        else if (t < 114688) { W = w3a; O = o3a; K = 128; N = 128; i = t - 98304; }
        else                 { W = w3b; O = o3b; K = 128; N = 64;  i = t - 114688; }
        int k = i / N, c = i % N;
        O[c * K + k] = f2b(W[i]);
    } else if (t < 222880) {
        ideg[t - 122880] = 0;
    } else if (t < 231072) {
        pooled[t - 222880] = 0.f;
    }
}

// ---- mega dispatch: gemm1 (counted-vmcnt stream) + CSR histogram -----------
__global__ __launch_bounds__(256) void gemm1_hist_k(const float* __restrict__ A,
                                                    const ushort_t* __restrict__ Wt,
                                                    ushort_t* __restrict__ C, int M,
                                                    const int* __restrict__ dst,
                                                    int* __restrict__ deg) {
    __shared__ __align__(16) float    Af[4][2048];   // 4 x 8 KB (64 rows x 32 k)
    __shared__ __align__(16) ushort_t Bl[4][4096];   // 4 x 8 KB (128 cols x 32 k)

    if (blockIdx.x >= G1_BLOCKS) {
        int b = blockIdx.x - G1_BLOCKS;
        int e0 = b * 1024 + threadIdx.x;
        #pragma unroll
        for (int p = 0; p < 4; ++p) {
            int e = e0 + p * 256;
            if (e < N_EDGES) atomicAdd(&deg[dst[e]], 1);
        }
        return;
    }

    constexpr int K = 384;
    const int tid  = threadIdx.x;
    const int lane = tid & 63;
    const int wid  = tid >> 6;
    const int wrow = wid >> 1;
    const int wcol = wid & 1;
    const int l15  = lane & 15;
    const int kg   = lane >> 4;
    const int row0 = blockIdx.x * 64;

    const int R0 = tid >> 3, cu = tid & 7;
    const int R1 = R0 + 32;
    int gr0 = row0 + R0; if (gr0 > M - 1) gr0 = M - 1;
    int gr1 = row0 + R1; if (gr1 > M - 1) gr1 = M - 1;
    const int as0 = (cu ^ (R0 & 7)) * 4;
    const int as1 = (cu ^ (R1 & 7)) * 4;
    const int col0 = tid >> 2, bu = tid & 3;
    const int col1 = col0 + 64;
    const int bs0 = (bu ^ (col0 & 3)) * 8;
    const int bs1 = (bu ^ (col1 & 3)) * 8;

    f32x4 acc[2][4];
    #pragma unroll
    for (int i = 0; i < 2; ++i)
        #pragma unroll
        for (int j = 0; j < 4; ++j)
            acc[i][j] = f32x4{0.f, 0.f, 0.f, 0.f};

    #pragma unroll
    for (int p = 0; p < 2; ++p) {
        int k0 = p * 32;
        gload16(A + (size_t)gr0 * K + k0 + as0, &Af[p][wid * 256]);
        gload16(A + (size_t)gr1 * K + k0 + as1, &Af[p][1024 + wid * 256]);
        gload16(Wt + (size_t)col0 * K + k0 + bs0, &Bl[p][wid * 512]);
        gload16(Wt + (size_t)col1 * K + k0 + bs1, &Bl[p][2048 + wid * 512]);
    }

    const int rA0 = wrow * 32 + l15;
    const int rA1 = rA0 + 16;
    const int sw0 = rA0 & 7;

    #pragma unroll
    for (int t = 0; t < 12; ++t) {
        if (t + 2 < 12) {
            int k0 = (t + 2) * 32;
            int buf = (t + 2) & 3;
            gload16(A + (size_t)gr0 * K + k0 + as0, &Af[buf][wid * 256]);
            gload16(A + (size_t)gr1 * K + k0 + as1, &Af[buf][1024 + wid * 256]);
            gload16(Wt + (size_t)col0 * K + k0 + bs0, &Bl[buf][wid * 512]);
            gload16(Wt + (size_t)col1 * K + k0 + bs1, &Bl[buf][2048 + wid * 512]);
        }
        if (t < 10)       asm volatile("s_waitcnt vmcnt(8)" ::: "memory");
        else if (t == 10) asm volatile("s_waitcnt vmcnt(4)" ::: "memory");
        else              asm volatile("s_waitcnt vmcnt(0)" ::: "memory");
        __builtin_amdgcn_s_barrier();
        __builtin_amdgcn_sched_barrier(0);

        const float*    Ab = Af[t & 3];
        const ushort_t* Bb = Bl[t & 3];
        float4 lo0 = *reinterpret_cast<const float4*>(Ab + rA0 * 32 + (((kg * 2)     ^ sw0) * 4));
        float4 hi0 = *reinterpret_cast<const float4*>(Ab + rA0 * 32 + (((kg * 2 + 1) ^ sw0) * 4));
        float4 lo1 = *reinterpret_cast<const float4*>(Ab + rA1 * 32 + (((kg * 2)     ^ sw0) * 4));
        float4 hi1 = *reinterpret_cast<const float4*>(Ab + rA1 * 32 + (((kg * 2 + 1) ^ sw0) * 4));
        bf16x8 a0, a1;
        a0[0] = (__bf16)lo0.x; a0[1] = (__bf16)lo0.y; a0[2] = (__bf16)lo0.z; a0[3] = (__bf16)lo0.w;
        a0[4] = (__bf16)hi0.x; a0[5] = (__bf16)hi0.y; a0[6] = (__bf16)hi0.z; a0[7] = (__bf16)hi0.w;
        a1[0] = (__bf16)lo1.x; a1[1] = (__bf16)lo1.y; a1[2] = (__bf16)lo1.z; a1[3] = (__bf16)lo1.w;
        a1[4] = (__bf16)hi1.x; a1[5] = (__bf16)hi1.y; a1[6] = (__bf16)hi1.z; a1[7] = (__bf16)hi1.w;
        #pragma unroll
        for (int j = 0; j < 4; ++j) {
            int col = wcol * 64 + j * 16 + l15;
            bf16x8 b = *reinterpret_cast<const bf16x8*>(Bb + col * 32 + ((kg ^ (col & 3)) * 8));
            acc[0][j] = __builtin_amdgcn_mfma_f32_16x16x32_bf16(a0, b, acc[0][j], 0, 0, 0);
            acc[1][j] = __builtin_amdgcn_mfma_f32_16x16x32_bf16(a1, b, acc[1][j], 0, 0, 0);
        }
    }

    __syncthreads();
    ushort_t* Es = (ushort_t*)&Af[0][0];
    #pragma unroll
    for (int i = 0; i < 2; ++i)
        #pragma unroll
        for (int j = 0; j < 4; ++j) {
            int col = wcol * 64 + j * 16 + l15;
            #pragma unroll
            for (int q = 0; q < 4; ++q) {
                int row = wrow * 32 + i * 16 + kg * 4 + q;
                Es[row * LDP + col] = f2b(acc[i][j][q]);
            }
        }
    __syncthreads();
    #pragma unroll
    for (int p = 0; p < 4; ++p) {
        int idx = tid + p * 256;
        int rr = idx >> 4, c16 = idx & 15;
        int gr = row0 + rr;
        if (gr < M)
            *reinterpret_cast<uint4*>(C + (size_t)gr * 128 + c16 * 8) =
                *reinterpret_cast<const uint4*>(&Es[rr * LDP + c16 * 8]);
    }
}

// ---------------- CSR scan chain ----------------
__global__ __launch_bounds__(256) void scan1_k(const int* __restrict__ deg,
                                               int* __restrict__ tmp,
                                               int* __restrict__ bsum) {
    __shared__ int s[256];
    int i = blockIdx.x * 256 + threadIdx.x;
    int t = threadIdx.x;
    s[t] = (i < N_NODES) ? deg[i] : 0;
    __syncthreads();
    for (int off = 1; off < 256; off <<= 1) {
        int v = (t >= off) ? s[t - off] : 0;
        __syncthreads();
        s[t] += v;
        __syncthreads();
    }
    if (i < N_NODES) tmp[i] = s[t];
    if (t == 255) bsum[blockIdx.x] = s[255];
}

__global__ __launch_bounds__(256) void scan23_k(const int* __restrict__ tmp,
                                                const int* __restrict__ deg,
                                                const int* __restrict__ bsum,
                                                int* __restrict__ row_start) {
    __shared__ int sb[256];
    int t = threadIdx.x;
    int partial = 0;
    for (int i = t; i < (int)blockIdx.x; i += 256) partial += bsum[i];
    sb[t] = partial;
    __syncthreads();
    for (int off = 128; off > 0; off >>= 1) {
        if (t < off) sb[t] += sb[t + off];
        __syncthreads();
    }
    int boff = sb[0];
    int i = blockIdx.x * 256 + t;
    if (i < N_NODES) row_start[i] = tmp[i] - deg[i] + boff;
}

__global__ __launch_bounds__(256) void fill_k(const int* __restrict__ src,
                                              const int* __restrict__ dst,
                                              int* __restrict__ row_start,
                                              int* __restrict__ csr_src) {
    int e = blockIdx.x * 256 + threadIdx.x;
    if (e >= N_EDGES) return;
    int idx = atomicAdd(&row_start[dst[e]], 1);
    csr_src[idx] = src[e];
}

// ======== fused layer: gather(16-wide batches, own-row prefetch)+BN+ReLU ->
//          LDS -> GEMM1(+b,relu) -> [TAIL: pool] or [GEMM2 -> Yout] =========
template<bool TAIL>
__global__ __launch_bounds__(256) void gather_mlp_k(
        const ushort_t* __restrict__ Yin,
        const int* __restrict__ csr, const int* __restrict__ rend,
        const int* __restrict__ deg,
        const float* __restrict__ epsp, const float* __restrict__ ba,
        const float* __restrict__ g, const float* __restrict__ be,
        const float* __restrict__ mm, const float* __restrict__ vv,
        const ushort_t* __restrict__ Wb, const float* __restrict__ bias1,
        const ushort_t* __restrict__ Wa2,
        ushort_t* __restrict__ Yout,
        const int* __restrict__ batch, float* __restrict__ pooled, int M) {
    constexpr int NJ1 = TAIL ? 2 : 4;       // N1 = 64 or 128
    __shared__ ushort_t Hl[64 * LDP];
    __shared__ ushort_t Xl[64 * LDP];       // f32 pool staging view for TAIL
    float* Fl = (float*)Xl;

    const int tid  = threadIdx.x;
    const int lane = tid & 63;
    const int wid  = tid >> 6;
    const int l15  = lane & 15;
    const int slot = lane >> 4;
    const int c0   = l15 * 8;
    const int row0 = blockIdx.x * 64;

    // ---- phase G: gather + BN + ReLU -> Hl (wave w owns rows w*16..w*16+15)
    {
        float ep = 1.0f + epsp[0];
        float sc[8], sh[8];
        #pragma unroll
        for (int jj = 0; jj < 8; ++jj) {
            int c = c0 + jj;
            float s = g[c] * rsqrtf(vv[c] + 1e-5f);
            sc[jj] = s;
            sh[jj] = (ba[c] - mm[c]) * s + be[c];
        }

        const int base = row0 + wid * 16;
        int cn = base; if (cn > M - 1) cn = M - 1;
        int end = rend[cn], d = deg[cn];
        int st = end - d;
        int nlim = (d > 64) ? 64 : d;
        int nb = (lane < nlim) ? csr[st + lane] : 0;
        uint4 ow = *reinterpret_cast<const uint4*>(Yin + (size_t)cn * 128 + c0);

        for (int nl = 0; nl < 16; ++nl) {
            int nxt = base + nl + 1; if (nxt > M - 1) nxt = M - 1;
            int nend = 0, nd = 0;
            if (nl < 15) { nend = rend[nxt]; nd = deg[nxt]; }   // prefetch meta

            float acc[8] = {0.f, 0.f, 0.f, 0.f, 0.f, 0.f, 0.f, 0.f};
            // 16 neighbors per iteration: 4 independent row loads per lane
            for (int j0 = 0; j0 < nlim; j0 += 16) {
                int jA = j0 + slot;
                int jB = j0 + 4 + slot;
                int jC = j0 + 8 + slot;
                int jD = j0 + 12 + slot;
                int iA = __shfl(nb, jA & 63);
                int iB = __shfl(nb, jB & 63);
                int iC = __shfl(nb, jC & 63);
                int iD = __shfl(nb, jD & 63);
                uint4 wa = *reinterpret_cast<const uint4*>(Yin + (size_t)iA * 128 + c0);
                uint4 wb = *reinterpret_cast<const uint4*>(Yin + (size_t)iB * 128 + c0);
                uint4 wc4 = *reinterpret_cast<const uint4*>(Yin + (size_t)iC * 128 + c0);
                uint4 wd = *reinterpret_cast<const uint4*>(Yin + (size_t)iD * 128 + c0);
                float fa = (jA < nlim) ? 1.f : 0.f;
                float fb = (jB < nlim) ? 1.f : 0.f;
                float fc = (jC < nlim) ? 1.f : 0.f;
                float fd = (jD < nlim) ? 1.f : 0.f;
                uint_t ua[4] = {wa.x, wa.y, wa.z, wa.w};
                uint_t ub[4] = {wb.x, wb.y, wb.z, wb.w};
                uint_t uc[4] = {wc4.x, wc4.y, wc4.z, wc4.w};
                uint_t ud[4] = {wd.x, wd.y, wd.z, wd.w};
                #pragma unroll
                for (int p = 0; p < 4; ++p) {
                    acc[2 * p]     += fa * b2f((ushort_t)(ua[p] & 0xffff));
                    acc[2 * p + 1] += fa * b2f((ushort_t)(ua[p] >> 16));
                    acc[2 * p]     += fb * b2f((ushort_t)(ub[p] & 0xffff));
                    acc[2 * p + 1] += fb * b2f((ushort_t)(ub[p] >> 16));
                    acc[2 * p]     += fc * b2f((ushort_t)(uc[p] & 0xffff));
                    acc[2 * p + 1] += fc * b2f((ushort_t)(uc[p] >> 16));
                    acc[2 * p]     += fd * b2f((ushort_t)(ud[p] & 0xffff));
                    acc[2 * p + 1] += fd * b2f((ushort_t)(ud[p] >> 16));
                }
            }
            for (int j = st + 64; j < end; ++j) {
                if (slot == 0) {
                    int idx = csr[j];
                    uint4 w = *reinterpret_cast<const uint4*>(Yin + (size_t)idx * 128 + c0);
                    uint_t uw[4] = {w.x, w.y, w.z, w.w};
                    #pragma unroll
                    for (int p = 0; p < 4; ++p) {
                        acc[2 * p]     += b2f((ushort_t)(uw[p] & 0xffff));
                        acc[2 * p + 1] += b2f((ushort_t)(uw[p] >> 16));
                    }
                }
            }

            // prefetch next node's indices + own row (overlaps reduce+BN+store)
            int nst = nend - nd;
            int nnlim = (nd > 64) ? 64 : nd;
            int nb2 = 0;
            uint4 ow2 = make_uint4(0, 0, 0, 0);
            if (nl < 15) {
                if (lane < nnlim) nb2 = csr[nst + lane];
                ow2 = *reinterpret_cast<const uint4*>(Yin + (size_t)nxt * 128 + c0);
            }

            #pragma unroll
            for (int jj = 0; jj < 8; ++jj) {
                acc[jj] += __shfl_xor(acc[jj], 16);
                acc[jj] += __shfl_xor(acc[jj], 32);
            }
            uint_t uo[4] = {ow.x, ow.y, ow.z, ow.w};
            ushort_t rr[8];
            #pragma unroll
            for (int p = 0; p < 4; ++p) {
                float o0 = b2f((ushort_t)(uo[p] & 0xffff));
                float o1 = b2f((ushort_t)(uo[p] >> 16));
                float t0 = sc[2 * p] * (ep * o0 + acc[2 * p]) + sh[2 * p];
                float t1 = sc[2 * p + 1] * (ep * o1 + acc[2 * p + 1]) + sh[2 * p + 1];
                rr[2 * p]     = f2b(fmaxf(t0, 0.f));
                rr[2 * p + 1] = f2b(fmaxf(t1, 0.f));
            }
            if (slot == 0) {
                uint4 packed;
                packed.x = (uint_t)rr[0] | ((uint_t)rr[1] << 16);
                packed.y = (uint_t)rr[2] | ((uint_t)rr[3] << 16);
                packed.z = (uint_t)rr[4] | ((uint_t)rr[5] << 16);
                packed.w = (uint_t)rr[6] | ((uint_t)rr[7] << 16);
                *reinterpret_cast<uint4*>(&Hl[(wid * 16 + nl) * LDP + c0]) = packed;
            }

            end = nend; d = nd; st = nst; nlim = nnlim; nb = nb2; ow = ow2;
        }
    }
    __syncthreads();

    // ---- MLP phase ----
    const int wrow = wid >> 1;
    const int wcol = wid & 1;
    const int kg   = lane >> 4;

    f32x4 acc1[2][NJ1];
    #pragma unroll
    for (int i = 0; i < 2; ++i)
        #pragma unroll
        for (int j = 0; j < NJ1; ++j)
            acc1[i][j] = f32x4{0.f, 0.f, 0.f, 0.f};
    #pragma unroll
    for (int kk = 0; kk < 4; ++kk) {
        bf16x8 a0 = *reinterpret_cast<const bf16x8*>(&Hl[(wrow * 32 + l15) * LDP + kk * 32 + kg * 8]);
        bf16x8 a1 = *reinterpret_cast<const bf16x8*>(&Hl[(wrow * 32 + 16 + l15) * LDP + kk * 32 + kg * 8]);
        #pragma unroll
        for (int j = 0; j < NJ1; ++j) {
            int col = wcol * (16 * NJ1) + j * 16 + l15;
            bf16x8 b = *reinterpret_cast<const bf16x8*>(Wb + (size_t)col * 128 + kk * 32 + kg * 8);
            acc1[0][j] = __builtin_amdgcn_mfma_f32_16x16x32_bf16(a0, b, acc1[0][j], 0, 0, 0);
            acc1[1][j] = __builtin_amdgcn_mfma_f32_16x16x32_bf16(a1, b, acc1[1][j], 0, 0, 0);
        }
    }

    if constexpr (TAIL) {
        #pragma unroll
        for (int i = 0; i < 2; ++i)
            #pragma unroll
            for (int j = 0; j < NJ1; ++j) {
                int col = wcol * 32 + j * 16 + l15;
                float bi = bias1[col];
                #pragma unroll
                for (int q = 0; q < 4; ++q) {
                    int row = wrow * 32 + i * 16 + kg * 4 + q;
                    Fl[row * FLDP + col] = fmaxf(acc1[i][j][q] + bi, 0.f);
                }
            }
        __syncthreads();
        int col = tid & 63;
        int qq  = tid >> 6;
        float a = 0.f;
        int cur = -1;
        for (int rr2 = 0; rr2 < 16; ++rr2) {
            int r = qq * 16 + rr2;
            int gr = row0 + r;
            if (gr >= M) break;
            int b = batch[gr];
            if (b != cur) {
                if (cur >= 0) atomicAdd(&pooled[cur * 64 + col], a);
                a = 0.f;
                cur = b;
            }
            a += Fl[r * FLDP + col];
        }
        if (cur >= 0) atomicAdd(&pooled[cur * 64 + col], a);
    } else {
        #pragma unroll
        for (int i = 0; i < 2; ++i)
            #pragma unroll
            for (int j = 0; j < NJ1; ++j) {
                int col = wcol * 64 + j * 16 + l15;
                float bi = bias1[col];
                #pragma unroll
                for (int q = 0; q < 4; ++q) {
                    int row = wrow * 32 + i * 16 + kg * 4 + q;
                    Xl[row * LDP + col] = f2b(fmaxf(acc1[i][j][q] + bi, 0.f));
                }
            }
        __syncthreads();

        f32x4 acc2[2][4];
        #pragma unroll
        for (int i = 0; i < 2; ++i)
            #pragma unroll
            for (int j = 0; j < 4; ++j)
                acc2[i][j] = f32x4{0.f, 0.f, 0.f, 0.f};
        #pragma unroll
        for (int kk = 0; kk < 4; ++kk) {
            bf16x8 a0 = *reinterpret_cast<const bf16x8*>(&Xl[(wrow * 32 + l15) * LDP + kk * 32 + kg * 8]);
            bf16x8 a1 = *reinterpret_cast<const bf16x8*>(&Xl[(wrow * 32 + 16 + l15) * LDP + kk * 32 + kg * 8]);
            #pragma unroll
            for (int j = 0; j < 4; ++j) {
                int col = wcol * 64 + j * 16 + l15;
                bf16x8 b = *reinterpret_cast<const bf16x8*>(Wa2 + (size_t)col * 128 + kk * 32 + kg * 8);
                acc2[0][j] = __builtin_amdgcn_mfma_f32_16x16x32_bf16(a0, b, acc2[0][j], 0, 0, 0);
                acc2[1][j] = __builtin_amdgcn_mfma_f32_16x16x32_bf16(a1, b, acc2[1][j], 0, 0, 0);
            }
        }
        __syncthreads();   // Hl reads (GEMM1) done; reuse Hl for output staging
        #pragma unroll
        for (int i = 0; i < 2; ++i)
            #pragma unroll
            for (int j = 0; j < 4; ++j) {
                int col = wcol * 64 + j * 16 + l15;
                #pragma unroll
                for (int q = 0; q < 4; ++q) {
                    int row = wrow * 32 + i * 16 + kg * 4 + q;
                    Hl[row * LDP + col] = f2b(acc2[i][j][q]);
                }
            }
        __syncthreads();
        #pragma unroll
        for (int p = 0; p < 4; ++p) {
            int idx = tid + p * 256;
            int r = idx >> 4, c16 = idx & 15;
            int gr = row0 + r;
            if (gr < M)
                *reinterpret_cast<uint4*>(Yout + (size_t)gr * 128 + c16 * 8) =
                    *reinterpret_cast<const uint4*>(&Hl[r * LDP + c16 * 8]);
        }
    }
}

// ---------------- classifier ----------------
__global__ __launch_bounds__(256) void classifier_k(const float* __restrict__ pooled,
                                                    const float* __restrict__ wc,
                                                    const float* __restrict__ bc,
                                                    float* __restrict__ out) {
    int t = threadIdx.x;
    int gidx = t >> 1, c = t & 1;
    float s = bc[c];
    #pragma unroll
    for (int k = 0; k < 64; ++k)
        s += pooled[gidx * 64 + k] * wc[k * 2 + c];
    out[gidx * 2 + c] = s;
}

extern "C" void kernel_launch(void* const* d_in, const int* in_sizes, int n_in,
                              void* d_out, int out_size, void* d_ws, size_t ws_size,
                              hipStream_t stream) {
    const float* x     = (const float*)d_in[0];
    const int*   ei    = (const int*)d_in[1];
    const int*   src   = ei;
    const int*   dst   = ei + N_EDGES;
    const int*   batch = (const int*)d_in[2];
    const float* eps1 = (const float*)d_in[3];
    const float* w1a  = (const float*)d_in[4];
    const float* b1a  = (const float*)d_in[5];
    const float* g1   = (const float*)d_in[6];
    const float* be1  = (const float*)d_in[7];
    const float* m1   = (const float*)d_in[8];
    const float* v1   = (const float*)d_in[9];
    const float* w1b  = (const float*)d_in[10];
    const float* b1b  = (const float*)d_in[11];
    const float* eps2 = (const float*)d_in[12];
    const float* w2a  = (const float*)d_in[13];
    const float* b2a  = (const float*)d_in[14];
    const float* g2   = (const float*)d_in[15];
    const float* be2  = (const float*)d_in[16];
    const float* m2   = (const float*)d_in[17];
    const float* v2   = (const float*)d_in[18];
    const float* w2b  = (const float*)d_in[19];
    const float* b2b  = (const float*)d_in[20];
    const float* eps3 = (const float*)d_in[21];
    const float* w3a  = (const float*)d_in[22];
    const float* b3a  = (const float*)d_in[23];
    const float* g3   = (const float*)d_in[24];
    const float* be3  = (const float*)d_in[25];
    const float* m3   = (const float*)d_in[26];
    const float* v3   = (const float*)d_in[27];
    const float* w3b  = (const float*)d_in[28];
    const float* b3b  = (const float*)d_in[29];
    const float* wc   = (const float*)d_in[30];
    const float* bc   = (const float*)d_in[31];
    float* out = (float*)d_out;

    // workspace layout
    ushort_t* Y = (ushort_t*)d_ws;             // [100000,128] bf16
    ushort_t* H = Y + 12800000;                // [100000,128] bf16 (ping-pong)
    ushort_t* wt1a = H + 12800000;             // 384*128
    ushort_t* wt1b = wt1a + 49152;             // 128*128
    ushort_t* wt2a = wt1b + 16384;
    ushort_t* wt2b = wt2a + 16384;
    ushort_t* wt3a = wt2b + 16384;
    ushort_t* wt3b = wt3a + 16384;             // 64*128
    float* pooled = (float*)(wt3b + 8192);     // [128,64]
    int* ideg = (int*)(pooled + 8192);         // [100000]
    int* irow = ideg + N_NODES;
    int* itmp = irow + N_NODES;
    int* icsr = itmp + N_NODES;                // [800000]
    int* ibsum = icsr + N_EDGES;               // [391]

    const int M = N_NODES;
    const int gLayer = (M + 63) / 64;          // 1563
    const int gEdge = (N_EDGES + 255) / 256;   // 3125
    const int gNode = NB_SCAN;                 // 391

    // ---- 1: weight transposes + zero ideg + zero pooled ----
    wt_all_k<<<903, 256, 0, stream>>>(w1a, w1b, w2a, w2b, w3a, w3b,
                                      wt1a, wt1b, wt2a, wt2b, wt3a, wt3b,
                                      ideg, pooled);

    // ---- 2: gemm1 (counted-vmcnt stream) + histogram ----
    gemm1_hist_k<<<G1_BLOCKS + HIST_BLOCKS, 256, 0, stream>>>(x, wt1a, Y, M, dst, ideg);

    // ---- 3-5: scan chain + fill ----
    scan1_k<<<gNode, 256, 0, stream>>>(ideg, itmp, ibsum);
    scan23_k<<<gNode, 256, 0, stream>>>(itmp, ideg, ibsum, irow);
    fill_k<<<gEdge, 256, 0, stream>>>(src, dst, irow, icsr);

    // ---- 6-8: fused layers ----
    gather_mlp_k<false><<<gLayer, 256, 0, stream>>>(
        Y, icsr, irow, ideg, eps1, b1a, g1, be1, m1, v1,
        wt1b, b1b, wt2a, H, nullptr, nullptr, M);
    gather_mlp_k<false><<<gLayer, 256, 0, stream>>>(
        H, icsr, irow, ideg, eps2, b2a, g2, be2, m2, v2,
        wt2b, b2b, wt3a, Y, nullptr, nullptr, M);
    gather_mlp_k<true><<<gLayer, 256, 0, stream>>>(
        Y, icsr, irow, ideg, eps3, b3a, g3, be3, m3, v3,
        wt3b, b3b, nullptr, nullptr, batch, pooled, M);

    // ---- 9: classifier ----
    classifier_k<<<1, 256, 0, stream>>>(pooled, wc, bc, out);
}